// Round 1
// baseline (832.389 us; speedup 1.0000x reference)
//
#include <hip/hip_runtime.h>
#include <hip/hip_bf16.h>
#include <math.h>

// ---------------- problem constants ----------------
#define BATCH   1024
#define NUMPT   100
#define NVAR    11
#define NOBS    10
#define HID     1024
#define INPD    55
#define TRAJD   200
#define ENCIN   (INPD + TRAJD)   // 255
#define DECIN   (2 + INPD)       // 57

#define T_FIN_C   15.0f
#define K_P_C     20.0f
#define K_D_C     8.944271909999159f   // 2*sqrt(20)
#define K_P_V_C   20.0f
#define A_OBS_C   8.0f
#define B_OBS_C   4.2f
#define RHO_V_C      1.0f
#define RHO_PROJ_C   1.0f
#define RHO_LANE_C   100.0f
#define RHO_OBS_C    100.0f
#define RHO_OFFSET_C 1.0f
#define RHO_INEQ_C   100.0f
#define V_MIN_C   0.1f
#define V_MAX_C   30.0f
#define A_MAX_C   8.0f
#define MAXIT     20

// workspace layout (float offsets)
#define WS_INV1X  0      // 14x14
#define WS_INV1Y  256    // 15x15
#define WS_INV2X  512    // 14x14
#define WS_INV2Y  768    // 15x15
#define WS_SVD    1024   // 4x11 chunk-summed A_vd
#define WS_SPD    1088   // 4x11 chunk-summed A_pd
#define WS_BIG    2048

// ---------------------------------------------------------------------------
// Precompute: build the 4 KKT matrices from P/Pdot/Pddot and invert them
// (Gauss-Jordan WITH partial pivoting: cost1_x's 11x11 block is singular —
// Bernstein all-ones null vector — so pivoting is mandatory at step 10).
// grid = 4 blocks (one matrix each), 256 threads.
// ---------------------------------------------------------------------------
__global__ __launch_bounds__(256) void precompute_kernel(
    const float* __restrict__ Pg, const float* __restrict__ Pdg,
    const float* __restrict__ Pddg, float* __restrict__ ws)
{
    __shared__ float sP[NUMPT*NVAR], sPd[NUMPT*NVAR], sPdd[NUMPT*NVAR];
    __shared__ float aug[15][31];
    __shared__ float fcol[15];
    __shared__ float s_pivinv;
    __shared__ int   s_pidx;
    const int tid = threadIdx.x, bid = blockIdx.x;

    for (int i = tid; i < NUMPT*NVAR; i += blockDim.x) {
        sP[i] = Pg[i]; sPd[i] = Pdg[i]; sPdd[i] = Pddg[i];
    }
    for (int i = tid; i < 15*31; i += blockDim.x) (&aug[0][0])[i] = 0.0f;
    __syncthreads();

    const int N = (bid == 0 || bid == 2) ? 14 : 15;

    // cost block (11x11)
    if (tid < 121) {
        const int i = tid / 11, j = tid % 11;
        float s = 0.0f;
        if (bid == 0) {          // cost_smooth + RHO_V * Avd^T Avd
            for (int t = 0; t < NUMPT; ++t) {
                float pdd_i = sPdd[t*NVAR+i], pdd_j = sPdd[t*NVAR+j];
                float av_i = pdd_i - K_P_V_C * sPd[t*NVAR+i];
                float av_j = pdd_j - K_P_V_C * sPd[t*NVAR+j];
                s += pdd_i*pdd_j + RHO_V_C * av_i*av_j;
            }
        } else if (bid == 1) {   // cost_smooth + RHO_OFFSET * Apd^T Apd
            for (int t = 0; t < NUMPT; ++t) {
                float pdd_i = sPdd[t*NVAR+i], pdd_j = sPdd[t*NVAR+j];
                float ap_i = pdd_i - K_P_C*sP[t*NVAR+i] - K_D_C*sPd[t*NVAR+i];
                float ap_j = pdd_j - K_P_C*sP[t*NVAR+j] - K_D_C*sPd[t*NVAR+j];
                s += pdd_i*pdd_j + RHO_OFFSET_C * ap_i*ap_j;
            }
        } else {                 // cost2_x (+ lane term for bid==3)
            float obs_w = RHO_OBS_C * (float)NOBS;
            if (bid == 3) obs_w += RHO_LANE_C * 2.0f;
            for (int t = 0; t < NUMPT; ++t) {
                float p_i = sP[t*NVAR+i],   p_j = sP[t*NVAR+j];
                float pd_i = sPd[t*NVAR+i], pd_j = sPd[t*NVAR+j];
                float pdd_i = sPdd[t*NVAR+i], pdd_j = sPdd[t*NVAR+j];
                s += obs_w*p_i*p_j + RHO_INEQ_C*(pdd_i*pdd_j + pd_i*pd_j);
            }
            if (i == j) s += RHO_PROJ_C;
        }
        aug[i][j] = s;
    }
    // equality-constraint rows/cols
    if (tid < 11) {
        const int i = tid;
        float a0 = sP[i], a1 = sPd[i], a2 = sPdd[i];
        aug[i][11] = a0; aug[11][i] = a0;
        aug[i][12] = a1; aug[12][i] = a1;
        aug[i][13] = a2; aug[13][i] = a2;
        if (N == 15) { float a3 = sPd[99*NVAR + i]; aug[i][14] = a3; aug[14][i] = a3; }
    }
    if (tid < N) aug[tid][N + tid] = 1.0f;

    // chunk sums S_vd / S_pd (block 0 only; independent of GJ below)
    if (bid == 0 && tid < 44) {
        const int c = tid / 11, k = tid % 11;
        float sv = 0.0f, sp = 0.0f;
        for (int t = 25*c; t < 25*c + 25; ++t) {
            float p = sP[t*NVAR+k], pd = sPd[t*NVAR+k], pdd = sPdd[t*NVAR+k];
            sv += pdd - K_P_V_C * pd;
            sp += pdd - K_P_C * p - K_D_C * pd;
        }
        ws[WS_SVD + tid] = sv;
        ws[WS_SPD + tid] = sp;
    }
    __syncthreads();

    // Gauss-Jordan with partial pivoting on [M | I]
    for (int k = 0; k < N; ++k) {
        if (tid == 0) {
            int p = k; float best = fabsf(aug[k][k]);
            for (int i = k+1; i < N; ++i) {
                float v = fabsf(aug[i][k]);
                if (v > best) { best = v; p = i; }
            }
            s_pidx = p;
        }
        __syncthreads();
        const int p = s_pidx;
        if (p != k && tid < 2*N) {
            float tmp = aug[k][tid]; aug[k][tid] = aug[p][tid]; aug[p][tid] = tmp;
        }
        __syncthreads();
        if (tid == 0) s_pivinv = 1.0f / aug[k][k];
        __syncthreads();
        if (tid < 2*N) aug[k][tid] *= s_pivinv;
        __syncthreads();
        if (tid < N) fcol[tid] = (tid == k) ? 0.0f : aug[tid][k];
        __syncthreads();
        for (int idx = tid; idx < N*2*N; idx += blockDim.x) {
            const int i = idx / (2*N), j = idx % (2*N);
            if (i != k) aug[i][j] = fmaf(-fcol[i], aug[k][j], aug[i][j]);
        }
        __syncthreads();
    }

    float* dst = ws + (bid == 0 ? WS_INV1X : bid == 1 ? WS_INV1Y
                      : bid == 2 ? WS_INV2X : WS_INV2Y);
    for (int idx = tid; idx < N*N; idx += blockDim.x)
        dst[idx] = aug[idx / N][N + idx % N];
}

// ---------------------------------------------------------------------------
// Input prep: normalize inp, build encoder input [inp_n, traj_gt] and the
// inp_n part of decoder input.
// ---------------------------------------------------------------------------
__global__ __launch_bounds__(256) void prep_kernel(
    const float* __restrict__ inp, const float* __restrict__ traj,
    const float* __restrict__ mean, const float* __restrict__ stdv,
    float* __restrict__ enc_in, float* __restrict__ dec_in)
{
    const int b = blockIdx.x, t = threadIdx.x;
    if (t < INPD) {
        float v = (inp[b*INPD + t] - mean[t]) / stdv[t];
        enc_in[b*ENCIN + t] = v;
        dec_in[b*DECIN + 2 + t] = v;
    } else if (t < ENCIN) {
        enc_in[b*ENCIN + t] = traj[b*TRAJD + (t - INPD)];
    }
}

// ---------------------------------------------------------------------------
// Tiled fp32 GEMM: C[M,N] = act(A[M,K] @ W[K,N] + bias).  64x64 tile, BK=16,
// 256 threads, 4x4 micro-tile.  M,N multiples of 64; K arbitrary (guarded).
// ---------------------------------------------------------------------------
__global__ __launch_bounds__(256) void gemm_bias_act(
    const float* __restrict__ A, const float* __restrict__ W,
    const float* __restrict__ bias, float* __restrict__ C,
    int M, int N, int K, int relu)
{
    __shared__ float As[64][17];
    __shared__ float Bs[16][65];
    const int tid = threadIdx.x;
    const int tx = tid & 15, ty = tid >> 4;
    const int row0 = blockIdx.y * 64, col0 = blockIdx.x * 64;
    float acc[4][4] = {};

    for (int k0 = 0; k0 < K; k0 += 16) {
        {   // A tile: 64 rows x 16 k
            const int c = tid & 15, r = tid >> 4;
            #pragma unroll
            for (int p = 0; p < 4; ++p) {
                const int rr = r + 16*p, kk = k0 + c;
                As[rr][c] = (kk < K) ? A[(size_t)(row0 + rr)*K + kk] : 0.0f;
            }
        }
        {   // W tile: 16 k x 64 cols
            const int n = tid & 63, c2 = tid >> 6;
            #pragma unroll
            for (int p = 0; p < 4; ++p) {
                const int kk = k0 + c2 + 4*p;
                Bs[c2 + 4*p][n] = (kk < K) ? W[(size_t)kk*N + col0 + n] : 0.0f;
            }
        }
        __syncthreads();
        #pragma unroll
        for (int kk = 0; kk < 16; ++kk) {
            float a[4], bb[4];
            #pragma unroll
            for (int i = 0; i < 4; ++i) a[i] = As[ty*4 + i][kk];
            #pragma unroll
            for (int j = 0; j < 4; ++j) bb[j] = Bs[kk][tx*4 + j];
            #pragma unroll
            for (int i = 0; i < 4; ++i)
                #pragma unroll
                for (int j = 0; j < 4; ++j)
                    acc[i][j] = fmaf(a[i], bb[j], acc[i][j]);
        }
        __syncthreads();
    }
    #pragma unroll
    for (int i = 0; i < 4; ++i) {
        const int rr = row0 + ty*4 + i;
        #pragma unroll
        for (int j = 0; j < 4; ++j) {
            const int cc = col0 + tx*4 + j;
            float v = acc[i][j] + bias[cc];
            if (relu) v = fmaxf(v, 0.0f);
            C[(size_t)rr*N + cc] = v;
        }
    }
}

// ---------------------------------------------------------------------------
// mu/logvar/z fused: one wave per batch row. Writes z into dec_in[:,0:2].
// ---------------------------------------------------------------------------
__global__ __launch_bounds__(64) void z_kernel(
    const float* __restrict__ h, const float* __restrict__ wmu,
    const float* __restrict__ bmu, const float* __restrict__ wlv,
    const float* __restrict__ blv, const float* __restrict__ eps,
    float* __restrict__ dec_in)
{
    const int b = blockIdx.x, lane = threadIdx.x;
    float a0 = 0, a1 = 0, a2 = 0, a3 = 0;
    for (int hh = lane; hh < HID; hh += 64) {
        float v = h[b*HID + hh];
        a0 = fmaf(v, wmu[hh*2 + 0], a0);
        a1 = fmaf(v, wmu[hh*2 + 1], a1);
        a2 = fmaf(v, wlv[hh*2 + 0], a2);
        a3 = fmaf(v, wlv[hh*2 + 1], a3);
    }
    #pragma unroll
    for (int off = 32; off; off >>= 1) {
        a0 += __shfl_down(a0, off);
        a1 += __shfl_down(a1, off);
        a2 += __shfl_down(a2, off);
        a3 += __shfl_down(a3, off);
    }
    if (lane == 0) {
        float mu0 = a0 + bmu[0], mu1 = a1 + bmu[1];
        float lv0 = a2 + blv[0], lv1 = a3 + blv[1];
        dec_in[b*DECIN + 0] = fmaf(expf(0.5f*lv0), eps[b*2 + 0], mu0);
        dec_in[b*DECIN + 1] = fmaf(expf(0.5f*lv1), eps[b*2 + 1], mu1);
    }
}

// ---------------------------------------------------------------------------
// Final decoder layer (N=8): one wave per batch row.
// ---------------------------------------------------------------------------
__global__ __launch_bounds__(64) void out8_kernel(
    const float* __restrict__ h, const float* __restrict__ w3,
    const float* __restrict__ b3, float* __restrict__ nn_out)
{
    const int b = blockIdx.x, lane = threadIdx.x;
    float acc[8] = {};
    for (int hh = lane; hh < HID; hh += 64) {
        float v = h[b*HID + hh];
        #pragma unroll
        for (int j = 0; j < 8; ++j) acc[j] = fmaf(v, w3[hh*8 + j], acc[j]);
    }
    #pragma unroll
    for (int j = 0; j < 8; ++j)
        #pragma unroll
        for (int off = 32; off; off >>= 1) acc[j] += __shfl_down(acc[j], off);
    if (lane == 0)
        for (int j = 0; j < 8; ++j) nn_out[b*8 + j] = acc[j] + b3[j];
}

// ---------------------------------------------------------------------------
// Batched ADMM solver: one block per batch element, 20 iterations.
// All trig eliminated analytically: cos/sin(atan2(y,x)) = {x,y}*rsqrt(x^2+y^2),
// d_v/d_a are clipped hypots.
// ---------------------------------------------------------------------------
__global__ __launch_bounds__(128) void solver_kernel(
    const float* __restrict__ nn_out, const float* __restrict__ inp,
    const float* __restrict__ ise, const float* __restrict__ yub_p,
    const float* __restrict__ ylb_p,
    const float* __restrict__ Pg, const float* __restrict__ Pdg,
    const float* __restrict__ Pddg,
    const float* __restrict__ ws, float* __restrict__ out)
{
    __shared__ float sP[NUMPT*NVAR], sPd[NUMPT*NVAR], sPdd[NUMPT*NVAR];
    __shared__ float i2x[196], i2y[225];
    __shared__ float arr[14][NUMPT];   // per-t reduction operands (reused as inv1 scratch)
    __shared__ float cx[11], cy[11], lx[11], ly[11];
    __shared__ float cbx[11], cby[11], linx[11], liny[11], ncx[11], ncy[11];
    __shared__ float obsx[NOBS], obsy[NOBS], obsvx[NOBS], obsvy[NOBS];
    __shared__ float nn[8], lcx[11], lcy[11];

    const int b = blockIdx.x, tid = threadIdx.x;

    for (int i = tid; i < NUMPT*NVAR; i += 128) {
        sP[i] = Pg[i]; sPd[i] = Pdg[i]; sPdd[i] = Pddg[i];
    }
    for (int i = tid; i < 196; i += 128) i2x[i] = ws[WS_INV2X + i];
    for (int i = tid; i < 225; i += 128) i2y[i] = ws[WS_INV2Y + i];
    float* i1x = &arr[0][0];
    float* i1y = &arr[0][0] + 196;
    for (int i = tid; i < 196; i += 128) i1x[i] = ws[WS_INV1X + i];
    for (int i = tid; i < 225; i += 128) i1y[i] = ws[WS_INV1Y + i];
    if (tid < NOBS) {
        obsx[tid]  = inp[b*INPD + 5 + 5*tid];
        obsy[tid]  = inp[b*INPD + 6 + 5*tid];
        obsvx[tid] = inp[b*INPD + 7 + 5*tid];
        obsvy[tid] = inp[b*INPD + 8 + 5*tid];
    }
    if (tid < 8) nn[tid] = nn_out[b*8 + tid];
    __syncthreads();

    const float vx0 = ise[b*4 + 2], vy0 = ise[b*4 + 3];
    const float yub = yub_p[b], ylb = ylb_p[b];

    // lincost from nn_out via chunk-summed A_vd/A_pd
    if (tid < 11) {
        float sx_ = 0.0f, sy_ = 0.0f;
        #pragma unroll
        for (int c = 0; c < 4; ++c) {
            sx_ = fmaf(nn[c],     ws[WS_SVD + c*11 + tid], sx_);
            sy_ = fmaf(nn[4 + c], ws[WS_SPD + c*11 + tid], sy_);
        }
        lcx[tid] = RHO_V_C * K_P_V_C * sx_;
        lcy[tid] = RHO_OFFSET_C * K_P_C * sy_;
    }
    __syncthreads();
    // c_bar = ([-lincost, b_eq] @ inv1^T)[:11] ; b_eq nonzero only at col 12
    if (tid < 11) {
        const int k = tid;
        float ax = vx0 * i1x[k*14 + 12];
        float ay = vy0 * i1y[k*15 + 12];
        #pragma unroll
        for (int j = 0; j < 11; ++j) {
            ax = fmaf(-lcx[j], i1x[k*14 + j], ax);
            ay = fmaf(-lcy[j], i1y[k*15 + j], ay);
        }
        cbx[k] = ax; cby[k] = ay;
        cx[k] = ax; cy[k] = ay;
        lx[k] = 0.0f; ly[k] = 0.0f;
    }
    __syncthreads();

    for (int it = 0; it < MAXIT; ++it) {
        // -------- phase A: per-timepoint quantities (threads 0..99) --------
        if (tid < NUMPT) {
            const int t = tid;
            const float* rP = &sP[t*NVAR];
            const float* rPd = &sPd[t*NVAR];
            const float* rPdd = &sPdd[t*NVAR];
            float px = 0, pxd = 0, pxdd = 0, py = 0, pyd = 0, pydd = 0;
            #pragma unroll
            for (int k = 0; k < 11; ++k) {
                float cxv = cx[k], cyv = cy[k];
                px   = fmaf(cxv, rP[k],   px);
                pxd  = fmaf(cxv, rPd[k],  pxd);
                pxdd = fmaf(cxv, rPdd[k], pxdd);
                py   = fmaf(cyv, rP[k],   py);
                pyd  = fmaf(cyv, rPd[k],  pyd);
                pydd = fmaf(cyv, rPdd[k], pydd);
            }
            const float tt = (float)t * (T_FIN_C / 99.0f);

            float srxo = 0, sryo = 0, sbox = 0, sboy = 0;
            #pragma unroll
            for (int o = 0; o < NOBS; ++o) {
                float xo = fmaf(obsvx[o], tt, obsx[o]);
                float yo = fmaf(obsvy[o], tt, obsy[o]);
                float wc = px - xo, wsv = py - yo;
                float aw = A_OBS_C * wsv, bw = B_OBS_C * wc;
                float r2 = aw*aw + bw*bw;
                float ca, sa;
                if (r2 > 0.0f) { float ri = rsqrtf(r2); ca = bw*ri; sa = aw*ri; }
                else           { ca = 1.0f; sa = 0.0f; }
                float c1 = RHO_OBS_C * (A_OBS_C*A_OBS_C*ca*ca + B_OBS_C*B_OBS_C*sa*sa);
                float c2 = RHO_OBS_C * (A_OBS_C*wc*ca + B_OBS_C*wsv*sa);
                float d_o = fmaxf(1.0f, c2 / c1);
                float adc = A_OBS_C * d_o * ca, bds = B_OBS_C * d_o * sa;
                srxo += wc - adc;  sryo += wsv - bds;
                sbox += xo + adc;  sboy += yo + bds;
            }
            arr[0][t] = srxo; arr[1][t] = sryo;
            arr[2][t] = sbox; arr[3][t] = sboy;

            // velocity projection
            float rv2 = pxd*pxd + pyd*pyd, cv, sv, rv;
            if (rv2 > 0.0f) { float ri = rsqrtf(rv2); rv = rv2*ri; cv = pxd*ri; sv = pyd*ri; }
            else            { rv = 0.0f; cv = 1.0f; sv = 0.0f; }
            float dv = fminf(fmaxf(rv, V_MIN_C), V_MAX_C);
            arr[4][t] = pxd - dv*cv;  arr[5][t] = pyd - dv*sv;
            arr[6][t] = dv*cv;        arr[7][t] = dv*sv;

            // acceleration projection
            float ra2 = pxdd*pxdd + pydd*pydd, caa, saa, ra;
            if (ra2 > 0.0f) { float ri = rsqrtf(ra2); ra = ra2*ri; caa = pxdd*ri; saa = pydd*ri; }
            else            { ra = 0.0f; caa = 1.0f; saa = 0.0f; }
            float da = fminf(ra, A_MAX_C);
            arr[8][t]  = pxdd - da*caa;  arr[9][t]  = pydd - da*saa;
            arr[10][t] = da*caa;         arr[11][t] = da*saa;

            // lane
            float res_up = fmaxf(0.0f, py - yub), res_lo = fmaxf(0.0f, ylb - py);
            arr[12][t] = res_up - res_lo;
            float s_up = fmaxf(0.0f, yub - py), s_lo = fmaxf(0.0f, py - ylb);
            arr[13][t] = (yub + ylb) - s_up + s_lo;
        }
        __syncthreads();

        // -------- phase B: weighted reductions + lambda/lincost update ------
        if (tid < 22) {
            const int k = tid % 11;
            if (tid < 11) {
                float s1 = 0, s2 = 0, s3 = 0, s4 = 0, s5 = 0, s6 = 0;
                for (int t = 0; t < NUMPT; ++t) {
                    float p = sP[t*NVAR + k], pd = sPd[t*NVAR + k], pdd = sPdd[t*NVAR + k];
                    s1 = fmaf(arr[0][t],  p,   s1);
                    s2 = fmaf(arr[8][t],  pdd, s2);
                    s3 = fmaf(arr[4][t],  pd,  s3);
                    s4 = fmaf(arr[2][t],  p,   s4);
                    s5 = fmaf(arr[10][t], pdd, s5);
                    s6 = fmaf(arr[6][t],  pd,  s6);
                }
                float l = lx[k] - RHO_OBS_C*s1 - RHO_INEQ_C*s2 - RHO_INEQ_C*s3;
                lx[k] = l;
                linx[k] = -l - RHO_PROJ_C*cbx[k] - RHO_OBS_C*s4
                          - RHO_INEQ_C*s5 - RHO_INEQ_C*s6;
            } else {
                float s1 = 0, s2 = 0, s3 = 0, s4 = 0, s5 = 0, s6 = 0, s7 = 0, s8 = 0;
                for (int t = 0; t < NUMPT; ++t) {
                    float p = sP[t*NVAR + k], pd = sPd[t*NVAR + k], pdd = sPdd[t*NVAR + k];
                    s1 = fmaf(arr[1][t],  p,   s1);
                    s2 = fmaf(arr[9][t],  pdd, s2);
                    s3 = fmaf(arr[5][t],  pd,  s3);
                    s7 = fmaf(arr[12][t], p,   s7);
                    s4 = fmaf(arr[3][t],  p,   s4);
                    s5 = fmaf(arr[11][t], pdd, s5);
                    s6 = fmaf(arr[7][t],  pd,  s6);
                    s8 = fmaf(arr[13][t], p,   s8);
                }
                float l = ly[k] - RHO_OBS_C*s1 - RHO_INEQ_C*s2 - RHO_INEQ_C*s3
                          - RHO_LANE_C*s7;
                ly[k] = l;
                liny[k] = -l - RHO_PROJ_C*cby[k] - RHO_OBS_C*s4
                          - RHO_INEQ_C*s5 - RHO_INEQ_C*s6 - RHO_LANE_C*s8;
            }
        }
        __syncthreads();

        // -------- phase C: KKT solve via precomputed inverse ---------------
        if (tid < 22) {
            const int k = tid % 11;
            if (tid < 11) {
                float a = vx0 * i2x[k*14 + 12];
                #pragma unroll
                for (int j = 0; j < 11; ++j) a = fmaf(-linx[j], i2x[k*14 + j], a);
                ncx[k] = a;
            } else {
                float a = vy0 * i2y[k*15 + 12];
                #pragma unroll
                for (int j = 0; j < 11; ++j) a = fmaf(-liny[j], i2y[k*15 + j], a);
                ncy[k] = a;
            }
        }
        __syncthreads();
        if (tid < 11) { cx[tid] = ncx[tid]; cy[tid] = ncy[tid]; }
        __syncthreads();
    }

    if (tid < 11) {
        out[b*22 + tid]      = cx[tid];
        out[b*22 + 11 + tid] = cy[tid];
    }
}

// ---------------------------------------------------------------------------
extern "C" void kernel_launch(void* const* d_in, const int* in_sizes, int n_in,
                              void* d_out, int out_size, void* d_ws, size_t ws_size,
                              hipStream_t stream)
{
    (void)in_sizes; (void)n_in; (void)out_size; (void)ws_size;
    const float* inp    = (const float*)d_in[0];
    const float* ise    = (const float*)d_in[1];
    const float* traj   = (const float*)d_in[2];
    const float* yub    = (const float*)d_in[3];
    const float* ylb    = (const float*)d_in[4];
    const float* eps    = (const float*)d_in[5];
    const float* enc_w1 = (const float*)d_in[6];
    const float* enc_b1 = (const float*)d_in[7];
    const float* enc_w2 = (const float*)d_in[8];
    const float* enc_b2 = (const float*)d_in[9];
    const float* wmu    = (const float*)d_in[10];
    const float* bmu    = (const float*)d_in[11];
    const float* wlv    = (const float*)d_in[12];
    const float* blv    = (const float*)d_in[13];
    const float* dec_w1 = (const float*)d_in[14];
    const float* dec_b1 = (const float*)d_in[15];
    const float* dec_w2 = (const float*)d_in[16];
    const float* dec_b2 = (const float*)d_in[17];
    const float* dec_w3 = (const float*)d_in[18];
    const float* dec_b3 = (const float*)d_in[19];
    const float* P      = (const float*)d_in[20];
    const float* Pd     = (const float*)d_in[21];
    const float* Pdd    = (const float*)d_in[22];
    const float* mean   = (const float*)d_in[23];
    const float* stdv   = (const float*)d_in[24];

    float* ws     = (float*)d_ws;
    float* enc_in = ws + WS_BIG;                     // B x 255
    float* dec_in = enc_in + (size_t)BATCH * ENCIN;  // B x 57
    float* hA     = dec_in + (size_t)BATCH * DECIN;  // B x 1024
    float* hB     = hA + (size_t)BATCH * HID;        // B x 1024
    float* nn     = hB + (size_t)BATCH * HID;        // B x 8
    float* outf   = (float*)d_out;

    precompute_kernel<<<4, 256, 0, stream>>>(P, Pd, Pdd, ws);
    prep_kernel<<<BATCH, 256, 0, stream>>>(inp, traj, mean, stdv, enc_in, dec_in);

    dim3 g16(HID/64, BATCH/64);
    gemm_bias_act<<<g16, 256, 0, stream>>>(enc_in, enc_w1, enc_b1, hA,
                                           BATCH, HID, ENCIN, 1);
    gemm_bias_act<<<g16, 256, 0, stream>>>(hA, enc_w2, enc_b2, hB,
                                           BATCH, HID, HID, 1);
    z_kernel<<<BATCH, 64, 0, stream>>>(hB, wmu, bmu, wlv, blv, eps, dec_in);
    gemm_bias_act<<<g16, 256, 0, stream>>>(dec_in, dec_w1, dec_b1, hA,
                                           BATCH, HID, DECIN, 1);
    gemm_bias_act<<<g16, 256, 0, stream>>>(hA, dec_w2, dec_b2, hB,
                                           BATCH, HID, HID, 1);
    out8_kernel<<<BATCH, 64, 0, stream>>>(hB, dec_w3, dec_b3, nn);
    solver_kernel<<<BATCH, 128, 0, stream>>>(nn, inp, ise, yub, ylb,
                                             P, Pd, Pdd, ws, outf);
}

// Round 2
// 592.771 us; speedup vs baseline: 1.4042x; 1.4042x over previous
//
#include <hip/hip_runtime.h>
#include <hip/hip_bf16.h>
#include <math.h>

// ---------------- problem constants ----------------
#define BATCH   1024
#define NUMPT   100
#define NVAR    11
#define NOBS    10
#define HID     1024
#define INPD    55
#define TRAJD   200
#define ENCIN   (INPD + TRAJD)   // 255
#define DECIN   (2 + INPD)       // 57

#define T_FIN_C   15.0f
#define K_P_C     20.0f
#define K_D_C     8.944271909999159f   // 2*sqrt(20)
#define K_P_V_C   20.0f
#define A_OBS_C   8.0f
#define B_OBS_C   4.2f
#define RHO_V_C      1.0f
#define RHO_PROJ_C   1.0f
#define RHO_LANE_C   100.0f
#define RHO_OBS_C    100.0f
#define RHO_OFFSET_C 1.0f
#define RHO_INEQ_C   100.0f
#define V_MIN_C   0.1f
#define V_MAX_C   30.0f
#define A_MAX_C   8.0f
#define MAXIT     20

// workspace layout (float offsets)
#define WS_INV1X  0      // 14x14
#define WS_INV1Y  256    // 15x15
#define WS_INV2X  512    // 14x14
#define WS_INV2Y  768    // 15x15
#define WS_SVD    1024   // 4x11 chunk-summed A_vd
#define WS_SPD    1088   // 4x11 chunk-summed A_pd
#define WS_QX     1152   // 11x11  Qx = cost2_x - I
#define WS_QY     1280   // 11x11  Qy = cost2_y - I
#define WS_BIG    2048

// ---------------------------------------------------------------------------
// Precompute: build the 4 KKT matrices and invert them (Gauss-Jordan with
// partial pivoting — cost1_x's 11x11 block is singular). Also stores
// Qx = cost2_x - I, Qy = cost2_y - I (needed by the solver's lincost algebra)
// and the chunk-summed A_vd/A_pd. grid = 4 blocks, 256 threads.
// ---------------------------------------------------------------------------
__global__ __launch_bounds__(256) void precompute_kernel(
    const float* __restrict__ Pg, const float* __restrict__ Pdg,
    const float* __restrict__ Pddg, float* __restrict__ ws)
{
    __shared__ float sP[NUMPT*NVAR], sPd[NUMPT*NVAR], sPdd[NUMPT*NVAR];
    __shared__ float aug[15][31];
    __shared__ float fcol[15];
    __shared__ float s_pivinv;
    __shared__ int   s_pidx;
    const int tid = threadIdx.x, bid = blockIdx.x;

    for (int i = tid; i < NUMPT*NVAR; i += blockDim.x) {
        sP[i] = Pg[i]; sPd[i] = Pdg[i]; sPdd[i] = Pddg[i];
    }
    for (int i = tid; i < 15*31; i += blockDim.x) (&aug[0][0])[i] = 0.0f;
    __syncthreads();

    const int N = (bid == 0 || bid == 2) ? 14 : 15;

    // cost block (11x11)
    if (tid < 121) {
        const int i = tid / 11, j = tid % 11;
        float s = 0.0f;
        if (bid == 0) {          // cost_smooth + RHO_V * Avd^T Avd
            for (int t = 0; t < NUMPT; ++t) {
                float pdd_i = sPdd[t*NVAR+i], pdd_j = sPdd[t*NVAR+j];
                float av_i = pdd_i - K_P_V_C * sPd[t*NVAR+i];
                float av_j = pdd_j - K_P_V_C * sPd[t*NVAR+j];
                s += pdd_i*pdd_j + RHO_V_C * av_i*av_j;
            }
        } else if (bid == 1) {   // cost_smooth + RHO_OFFSET * Apd^T Apd
            for (int t = 0; t < NUMPT; ++t) {
                float pdd_i = sPdd[t*NVAR+i], pdd_j = sPdd[t*NVAR+j];
                float ap_i = pdd_i - K_P_C*sP[t*NVAR+i] - K_D_C*sPd[t*NVAR+i];
                float ap_j = pdd_j - K_P_C*sP[t*NVAR+j] - K_D_C*sPd[t*NVAR+j];
                s += pdd_i*pdd_j + RHO_OFFSET_C * ap_i*ap_j;
            }
        } else {                 // cost2_x (+ lane term for bid==3)
            float obs_w = RHO_OBS_C * (float)NOBS;
            if (bid == 3) obs_w += RHO_LANE_C * 2.0f;
            for (int t = 0; t < NUMPT; ++t) {
                float p_i = sP[t*NVAR+i],   p_j = sP[t*NVAR+j];
                float pd_i = sPd[t*NVAR+i], pd_j = sPd[t*NVAR+j];
                float pdd_i = sPdd[t*NVAR+i], pdd_j = sPdd[t*NVAR+j];
                s += obs_w*p_i*p_j + RHO_INEQ_C*(pdd_i*pdd_j + pd_i*pd_j);
            }
            if (i == j) s += RHO_PROJ_C;
        }
        aug[i][j] = s;
    }
    // equality-constraint rows/cols
    if (tid < 11) {
        const int i = tid;
        float a0 = sP[i], a1 = sPd[i], a2 = sPdd[i];
        aug[i][11] = a0; aug[11][i] = a0;
        aug[i][12] = a1; aug[12][i] = a1;
        aug[i][13] = a2; aug[13][i] = a2;
        if (N == 15) { float a3 = sPd[99*NVAR + i]; aug[i][14] = a3; aug[14][i] = a3; }
    }
    if (tid < N) aug[tid][N + tid] = 1.0f;

    // chunk sums S_vd / S_pd (block 0 only)
    if (bid == 0 && tid < 44) {
        const int c = tid / 11, k = tid % 11;
        float sv = 0.0f, sp = 0.0f;
        for (int t = 25*c; t < 25*c + 25; ++t) {
            float p = sP[t*NVAR+k], pd = sPd[t*NVAR+k], pdd = sPdd[t*NVAR+k];
            sv += pdd - K_P_V_C * pd;
            sp += pdd - K_P_C * p - K_D_C * pd;
        }
        ws[WS_SVD + tid] = sv;
        ws[WS_SPD + tid] = sp;
    }
    __syncthreads();

    // stash Qx/Qy = cost2 - I before GJ destroys aug
    if ((bid == 2 || bid == 3) && tid < 121) {
        float v = aug[tid/11][tid%11];
        if (tid/11 == tid%11) v -= RHO_PROJ_C;
        ws[(bid == 2 ? WS_QX : WS_QY) + tid] = v;
    }

    // Gauss-Jordan with partial pivoting on [M | I]
    for (int k = 0; k < N; ++k) {
        if (tid == 0) {
            int p = k; float best = fabsf(aug[k][k]);
            for (int i = k+1; i < N; ++i) {
                float v = fabsf(aug[i][k]);
                if (v > best) { best = v; p = i; }
            }
            s_pidx = p;
        }
        __syncthreads();
        const int p = s_pidx;
        if (p != k && tid < 2*N) {
            float tmp = aug[k][tid]; aug[k][tid] = aug[p][tid]; aug[p][tid] = tmp;
        }
        __syncthreads();
        if (tid == 0) s_pivinv = 1.0f / aug[k][k];
        __syncthreads();
        if (tid < 2*N) aug[k][tid] *= s_pivinv;
        __syncthreads();
        if (tid < N) fcol[tid] = (tid == k) ? 0.0f : aug[tid][k];
        __syncthreads();
        for (int idx = tid; idx < N*2*N; idx += blockDim.x) {
            const int i = idx / (2*N), j = idx % (2*N);
            if (i != k) aug[i][j] = fmaf(-fcol[i], aug[k][j], aug[i][j]);
        }
        __syncthreads();
    }

    float* dst = ws + (bid == 0 ? WS_INV1X : bid == 1 ? WS_INV1Y
                      : bid == 2 ? WS_INV2X : WS_INV2Y);
    for (int idx = tid; idx < N*N; idx += blockDim.x)
        dst[idx] = aug[idx / N][N + idx % N];
}

// ---------------------------------------------------------------------------
__global__ __launch_bounds__(256) void prep_kernel(
    const float* __restrict__ inp, const float* __restrict__ traj,
    const float* __restrict__ mean, const float* __restrict__ stdv,
    float* __restrict__ enc_in, float* __restrict__ dec_in)
{
    const int b = blockIdx.x, t = threadIdx.x;
    if (t < INPD) {
        float v = (inp[b*INPD + t] - mean[t]) / stdv[t];
        enc_in[b*ENCIN + t] = v;
        dec_in[b*DECIN + 2 + t] = v;
    } else if (t < ENCIN) {
        enc_in[b*ENCIN + t] = traj[b*TRAJD + (t - INPD)];
    }
}

// ---------------------------------------------------------------------------
// Tiled fp32 GEMM: C = act(A@W + bias). 64x64 tile, BK=16, 256 threads,
// 4x4 micro-tile. A-tile stored k-major in LDS so BOTH fragments load as
// ds_read_b128.
// ---------------------------------------------------------------------------
__global__ __launch_bounds__(256) void gemm_bias_act(
    const float* __restrict__ A, const float* __restrict__ W,
    const float* __restrict__ bias, float* __restrict__ C,
    int M, int N, int K, int relu)
{
    __shared__ float As[16][68];   // [k][row]
    __shared__ float Bs[16][68];   // [k][col]
    const int tid = threadIdx.x;
    const int tx = tid & 15, ty = tid >> 4;
    const int row0 = blockIdx.y * 64, col0 = blockIdx.x * 64;
    float acc[4][4] = {};

    for (int k0 = 0; k0 < K; k0 += 16) {
        {   // A tile: 64 rows x 16 k, store transposed
            const int c = tid & 15, r = tid >> 4;
            const int kk = k0 + c;
            #pragma unroll
            for (int p = 0; p < 4; ++p) {
                const int rr = r + 16*p;
                As[c][rr] = (kk < K) ? A[(size_t)(row0 + rr)*K + kk] : 0.0f;
            }
        }
        {   // W tile: 16 k x 64 cols
            const int n = tid & 63, c2 = tid >> 6;
            #pragma unroll
            for (int p = 0; p < 4; ++p) {
                const int kk = k0 + c2 + 4*p;
                Bs[c2 + 4*p][n] = (kk < K) ? W[(size_t)kk*N + col0 + n] : 0.0f;
            }
        }
        __syncthreads();
        #pragma unroll
        for (int kk = 0; kk < 16; ++kk) {
            float4 a4 = *(const float4*)&As[kk][ty*4];
            float4 b4 = *(const float4*)&Bs[kk][tx*4];
            float a[4] = {a4.x, a4.y, a4.z, a4.w};
            float bb[4] = {b4.x, b4.y, b4.z, b4.w};
            #pragma unroll
            for (int i = 0; i < 4; ++i)
                #pragma unroll
                for (int j = 0; j < 4; ++j)
                    acc[i][j] = fmaf(a[i], bb[j], acc[i][j]);
        }
        __syncthreads();
    }
    #pragma unroll
    for (int i = 0; i < 4; ++i) {
        const int rr = row0 + ty*4 + i;
        #pragma unroll
        for (int j = 0; j < 4; ++j) {
            const int cc = col0 + tx*4 + j;
            float v = acc[i][j] + bias[cc];
            if (relu) v = fmaxf(v, 0.0f);
            C[(size_t)rr*N + cc] = v;
        }
    }
}

// ---------------------------------------------------------------------------
__global__ __launch_bounds__(64) void z_kernel(
    const float* __restrict__ h, const float* __restrict__ wmu,
    const float* __restrict__ bmu, const float* __restrict__ wlv,
    const float* __restrict__ blv, const float* __restrict__ eps,
    float* __restrict__ dec_in)
{
    const int b = blockIdx.x, lane = threadIdx.x;
    float a0 = 0, a1 = 0, a2 = 0, a3 = 0;
    for (int hh = lane; hh < HID; hh += 64) {
        float v = h[b*HID + hh];
        a0 = fmaf(v, wmu[hh*2 + 0], a0);
        a1 = fmaf(v, wmu[hh*2 + 1], a1);
        a2 = fmaf(v, wlv[hh*2 + 0], a2);
        a3 = fmaf(v, wlv[hh*2 + 1], a3);
    }
    #pragma unroll
    for (int off = 32; off; off >>= 1) {
        a0 += __shfl_down(a0, off);
        a1 += __shfl_down(a1, off);
        a2 += __shfl_down(a2, off);
        a3 += __shfl_down(a3, off);
    }
    if (lane == 0) {
        float mu0 = a0 + bmu[0], mu1 = a1 + bmu[1];
        float lv0 = a2 + blv[0], lv1 = a3 + blv[1];
        dec_in[b*DECIN + 0] = fmaf(expf(0.5f*lv0), eps[b*2 + 0], mu0);
        dec_in[b*DECIN + 1] = fmaf(expf(0.5f*lv1), eps[b*2 + 1], mu1);
    }
}

// ---------------------------------------------------------------------------
__global__ __launch_bounds__(64) void out8_kernel(
    const float* __restrict__ h, const float* __restrict__ w3,
    const float* __restrict__ b3, float* __restrict__ nn_out)
{
    const int b = blockIdx.x, lane = threadIdx.x;
    float acc[8] = {};
    for (int hh = lane; hh < HID; hh += 64) {
        float v = h[b*HID + hh];
        #pragma unroll
        for (int j = 0; j < 8; ++j) acc[j] = fmaf(v, w3[hh*8 + j], acc[j]);
    }
    #pragma unroll
    for (int j = 0; j < 8; ++j)
        #pragma unroll
        for (int off = 32; off; off >>= 1) acc[j] += __shfl_down(acc[j], off);
    if (lane == 0)
        for (int j = 0; j < 8; ++j) nn_out[b*8 + j] = acc[j] + b3[j];
}

// ---------------------------------------------------------------------------
// Batched ADMM solver, restructured:
//  Phase A (200 thr): 2 threads per timepoint; residual rows only.
//  Phase B (198 thr): 7 residual projections x 11 k x 2 t-chunks.
//  Phase B2 (22 thr): lam/lincost via  lin = -l + 2u - c_bar - Q c
//    (uses b_o = x - r_o, dv*cv = xd - rv, da*ca = xdd - ra,
//     (b_lane - s_lane)@A_lane = 2 P^T y - P^T res_lane; Q = cost2 - I).
//  Phase C (22 thr): KKT solve via precomputed inverse; double-buffered c.
// ---------------------------------------------------------------------------
__global__ __launch_bounds__(256) void solver_kernel(
    const float* __restrict__ nn_out, const float* __restrict__ inp,
    const float* __restrict__ ise, const float* __restrict__ yub_p,
    const float* __restrict__ ylb_p,
    const float* __restrict__ Pg, const float* __restrict__ Pdg,
    const float* __restrict__ Pddg,
    const float* __restrict__ ws, float* __restrict__ out)
{
    __shared__ float sP[NUMPT*NVAR], sPd[NUMPT*NVAR], sPdd[NUMPT*NVAR];
    __shared__ float i2x[196], i2y[225];
    __shared__ float Qx[121], Qy[121];
    __shared__ float rows[900];           // 9 residual rows; aliased for inv1 at init
    __shared__ float part[NVAR][20];
    __shared__ float cxb[2][NVAR], cyb[2][NVAR];
    __shared__ float lx[NVAR], ly[NVAR], cbx[NVAR], cby[NVAR];
    __shared__ float linx[NVAR], liny[NVAR];
    __shared__ float obsx[NOBS], obsy[NOBS], obsvx[NOBS], obsvy[NOBS];
    __shared__ float nn[8], lcx[NVAR], lcy[NVAR];

    float* R_SX0 = rows +   0;
    float* R_SX1 = rows + 100;
    float* R_SY0 = rows + 200;
    float* R_SY1 = rows + 300;
    float* R_VX  = rows + 400;
    float* R_VY  = rows + 500;
    float* R_AX  = rows + 600;
    float* R_AY  = rows + 700;
    float* R_LN  = rows + 800;

    const int b = blockIdx.x, tid = threadIdx.x;

    for (int i = tid; i < NUMPT*NVAR; i += 256) {
        sP[i] = Pg[i]; sPd[i] = Pdg[i]; sPdd[i] = Pddg[i];
    }
    for (int i = tid; i < 196; i += 256) i2x[i] = ws[WS_INV2X + i];
    for (int i = tid; i < 225; i += 256) i2y[i] = ws[WS_INV2Y + i];
    for (int i = tid; i < 121; i += 256) { Qx[i] = ws[WS_QX + i]; Qy[i] = ws[WS_QY + i]; }
    // inv1 staged into 'rows' (overwritten by phase A later)
    float* i1x = rows;          // 196
    float* i1y = rows + 200;    // 225
    for (int i = tid; i < 196; i += 256) i1x[i] = ws[WS_INV1X + i];
    for (int i = tid; i < 225; i += 256) i1y[i] = ws[WS_INV1Y + i];
    if (tid < NOBS) {
        obsx[tid]  = inp[b*INPD + 5 + 5*tid];
        obsy[tid]  = inp[b*INPD + 6 + 5*tid];
        obsvx[tid] = inp[b*INPD + 7 + 5*tid];
        obsvy[tid] = inp[b*INPD + 8 + 5*tid];
    }
    if (tid < 8) nn[tid] = nn_out[b*8 + tid];
    __syncthreads();

    const float vx0 = ise[b*4 + 2], vy0 = ise[b*4 + 3];
    const float yub = yub_p[b], ylb = ylb_p[b];

    if (tid < NVAR) {
        float sx_ = 0.0f, sy_ = 0.0f;
        #pragma unroll
        for (int c = 0; c < 4; ++c) {
            sx_ = fmaf(nn[c],     ws[WS_SVD + c*11 + tid], sx_);
            sy_ = fmaf(nn[4 + c], ws[WS_SPD + c*11 + tid], sy_);
        }
        lcx[tid] = RHO_V_C * K_P_V_C * sx_;
        lcy[tid] = RHO_OFFSET_C * K_P_C * sy_;
    }
    __syncthreads();
    if (tid < NVAR) {
        const int k = tid;
        float ax = vx0 * i1x[k*14 + 12];
        float ay = vy0 * i1y[k*15 + 12];
        #pragma unroll
        for (int j = 0; j < NVAR; ++j) {
            ax = fmaf(-lcx[j], i1x[k*14 + j], ax);
            ay = fmaf(-lcy[j], i1y[k*15 + j], ay);
        }
        cbx[k] = ax; cby[k] = ay;
        cxb[0][k] = ax; cyb[0][k] = ay;
        lx[k] = 0.0f; ly[k] = 0.0f;
    }
    __syncthreads();

    int cur = 0;
    for (int it = 0; it < MAXIT; ++it) {
        const float* cxc = cxb[cur];
        const float* cyc = cyb[cur];

        // -------- phase A: residual rows, 2 threads per timepoint ----------
        if (tid < 2*NUMPT) {
            const int t = tid >> 1, h = tid & 1;
            const float* rP = &sP[t*NVAR];
            float px = 0, py = 0;
            #pragma unroll
            for (int k = 0; k < NVAR; ++k) {
                px = fmaf(cxc[k], rP[k], px);
                py = fmaf(cyc[k], rP[k], py);
            }
            const float tt = (float)t * (T_FIN_C / 99.0f);

            if (h == 0) {
                const float* rPd = &sPd[t*NVAR];
                const float* rPdd = &sPdd[t*NVAR];
                float pxd = 0, pxdd = 0, pyd = 0, pydd = 0;
                #pragma unroll
                for (int k = 0; k < NVAR; ++k) {
                    float cxv = cxc[k], cyv = cyc[k];
                    pxd  = fmaf(cxv, rPd[k],  pxd);
                    pxdd = fmaf(cxv, rPdd[k], pxdd);
                    pyd  = fmaf(cyv, rPd[k],  pyd);
                    pydd = fmaf(cyv, rPdd[k], pydd);
                }
                // velocity projection
                float rv2 = pxd*pxd + pyd*pyd, cv, sv, rv;
                if (rv2 > 0.0f) { float ri = rsqrtf(rv2); rv = rv2*ri; cv = pxd*ri; sv = pyd*ri; }
                else            { rv = 0.0f; cv = 1.0f; sv = 0.0f; }
                float dv = fminf(fmaxf(rv, V_MIN_C), V_MAX_C);
                R_VX[t] = pxd - dv*cv;  R_VY[t] = pyd - dv*sv;
                // acceleration projection
                float ra2 = pxdd*pxdd + pydd*pydd, caa, saa, ra;
                if (ra2 > 0.0f) { float ri = rsqrtf(ra2); ra = ra2*ri; caa = pxdd*ri; saa = pydd*ri; }
                else            { ra = 0.0f; caa = 1.0f; saa = 0.0f; }
                float da = fminf(ra, A_MAX_C);
                R_AX[t] = pxdd - da*caa;  R_AY[t] = pydd - da*saa;
                // lane residual
                R_LN[t] = fmaxf(0.0f, py - yub) - fmaxf(0.0f, ylb - py);
            }
            // obstacle residuals: h==0 -> obs 0..3, h==1 -> obs 4..9
            float srx = 0, sry = 0;
            const int o0 = h ? 4 : 0, o1 = h ? NOBS : 4;
            for (int o = o0; o < o1; ++o) {
                float xo = fmaf(obsvx[o], tt, obsx[o]);
                float yo = fmaf(obsvy[o], tt, obsy[o]);
                float wc = px - xo, wsv = py - yo;
                float aw = A_OBS_C * wsv, bw = B_OBS_C * wc;
                float r2 = aw*aw + bw*bw;
                float ca, sa;
                if (r2 > 0.0f) { float ri = rsqrtf(r2); ca = bw*ri; sa = aw*ri; }
                else           { ca = 1.0f; sa = 0.0f; }
                float c1 = RHO_OBS_C * (A_OBS_C*A_OBS_C*ca*ca + B_OBS_C*B_OBS_C*sa*sa);
                float c2 = RHO_OBS_C * (A_OBS_C*wc*ca + B_OBS_C*wsv*sa);
                float d_o = fmaxf(1.0f, c2 / c1);
                srx += wc - A_OBS_C * d_o * ca;
                sry += wsv - B_OBS_C * d_o * sa;
            }
            if (h == 0) { R_SX0[t] = srx; R_SY0[t] = sry; }
            else        { R_SX1[t] = srx; R_SY1[t] = sry; }
        }
        __syncthreads();

        // -------- phase B: 7 projections x 11 k x 2 chunks = 198 dots ------
        if (tid < 198) {
            const int k = tid / 18, u = tid - k*18;
            const float* rp; const float* bp; int t0;
            if (u < 4)       { rp = (u & 2) ? R_SX1 : R_SX0; bp = sP;   t0 = (u & 1)*50; }
            else if (u < 6)  { rp = R_AX; bp = sPdd; t0 = (u - 4)*50; }
            else if (u < 8)  { rp = R_VX; bp = sPd;  t0 = (u - 6)*50; }
            else if (u < 12) { rp = (u & 2) ? R_SY1 : R_SY0; bp = sP;   t0 = (u & 1)*50; }
            else if (u < 14) { rp = R_AY; bp = sPdd; t0 = (u - 12)*50; }
            else if (u < 16) { rp = R_VY; bp = sPd;  t0 = (u - 14)*50; }
            else             { rp = R_LN; bp = sP;   t0 = (u - 16)*50; }
            float s = 0.0f;
            for (int t = t0; t < t0 + 50; ++t)
                s = fmaf(rp[t], bp[t*NVAR + k], s);
            part[k][u] = s;
        }
        __syncthreads();

        // -------- phase B2: lambda + lincost assembly ----------------------
        if (tid < 22) {
            const int k = (tid < 11) ? tid : tid - 11;
            if (tid < 11) {
                float s = 0.0f;
                #pragma unroll
                for (int u = 0; u < 8; ++u) s += part[k][u];
                float ux = RHO_OBS_C * s;      // all rho terms = 100
                float q = 0.0f;
                #pragma unroll
                for (int j = 0; j < NVAR; ++j) q = fmaf(Qx[k*11 + j], cxc[j], q);
                float l = lx[k];
                lx[k] = l - ux;
                linx[k] = -l + 2.0f*ux - RHO_PROJ_C*cbx[k] - q;
            } else {
                float s = 0.0f;
                #pragma unroll
                for (int u = 8; u < 18; ++u) s += part[k][u];
                float uy = RHO_OBS_C * s;
                float q = 0.0f;
                #pragma unroll
                for (int j = 0; j < NVAR; ++j) q = fmaf(Qy[k*11 + j], cyc[j], q);
                float l = ly[k];
                ly[k] = l - uy;
                liny[k] = -l + 2.0f*uy - RHO_PROJ_C*cby[k] - q;
            }
        }
        __syncthreads();

        // -------- phase C: KKT solve via precomputed inverse ---------------
        if (tid < 22) {
            const int k = (tid < 11) ? tid : tid - 11;
            if (tid < 11) {
                float a = vx0 * i2x[k*14 + 12];
                #pragma unroll
                for (int j = 0; j < NVAR; ++j) a = fmaf(-linx[j], i2x[k*14 + j], a);
                cxb[cur ^ 1][k] = a;
            } else {
                float a = vy0 * i2y[k*15 + 12];
                #pragma unroll
                for (int j = 0; j < NVAR; ++j) a = fmaf(-liny[j], i2y[k*15 + j], a);
                cyb[cur ^ 1][k] = a;
            }
        }
        cur ^= 1;
        __syncthreads();
    }

    if (tid < NVAR) {
        out[b*22 + tid]      = cxb[cur][tid];
        out[b*22 + 11 + tid] = cyb[cur][tid];
    }
}

// ---------------------------------------------------------------------------
extern "C" void kernel_launch(void* const* d_in, const int* in_sizes, int n_in,
                              void* d_out, int out_size, void* d_ws, size_t ws_size,
                              hipStream_t stream)
{
    (void)in_sizes; (void)n_in; (void)out_size; (void)ws_size;
    const float* inp    = (const float*)d_in[0];
    const float* ise    = (const float*)d_in[1];
    const float* traj   = (const float*)d_in[2];
    const float* yub    = (const float*)d_in[3];
    const float* ylb    = (const float*)d_in[4];
    const float* eps    = (const float*)d_in[5];
    const float* enc_w1 = (const float*)d_in[6];
    const float* enc_b1 = (const float*)d_in[7];
    const float* enc_w2 = (const float*)d_in[8];
    const float* enc_b2 = (const float*)d_in[9];
    const float* wmu    = (const float*)d_in[10];
    const float* bmu    = (const float*)d_in[11];
    const float* wlv    = (const float*)d_in[12];
    const float* blv    = (const float*)d_in[13];
    const float* dec_w1 = (const float*)d_in[14];
    const float* dec_b1 = (const float*)d_in[15];
    const float* dec_w2 = (const float*)d_in[16];
    const float* dec_b2 = (const float*)d_in[17];
    const float* dec_w3 = (const float*)d_in[18];
    const float* dec_b3 = (const float*)d_in[19];
    const float* P      = (const float*)d_in[20];
    const float* Pd     = (const float*)d_in[21];
    const float* Pdd    = (const float*)d_in[22];
    const float* mean   = (const float*)d_in[23];
    const float* stdv   = (const float*)d_in[24];

    float* ws     = (float*)d_ws;
    float* enc_in = ws + WS_BIG;                     // B x 255
    float* dec_in = enc_in + (size_t)BATCH * ENCIN;  // B x 57
    float* hA     = dec_in + (size_t)BATCH * DECIN;  // B x 1024
    float* hB     = hA + (size_t)BATCH * HID;        // B x 1024
    float* nn     = hB + (size_t)BATCH * HID;        // B x 8
    float* outf   = (float*)d_out;

    precompute_kernel<<<4, 256, 0, stream>>>(P, Pd, Pdd, ws);
    prep_kernel<<<BATCH, 256, 0, stream>>>(inp, traj, mean, stdv, enc_in, dec_in);

    dim3 g16(HID/64, BATCH/64);
    gemm_bias_act<<<g16, 256, 0, stream>>>(enc_in, enc_w1, enc_b1, hA,
                                           BATCH, HID, ENCIN, 1);
    gemm_bias_act<<<g16, 256, 0, stream>>>(hA, enc_w2, enc_b2, hB,
                                           BATCH, HID, HID, 1);
    z_kernel<<<BATCH, 64, 0, stream>>>(hB, wmu, bmu, wlv, blv, eps, dec_in);
    gemm_bias_act<<<g16, 256, 0, stream>>>(dec_in, dec_w1, dec_b1, hA,
                                           BATCH, HID, DECIN, 1);
    gemm_bias_act<<<g16, 256, 0, stream>>>(hA, dec_w2, dec_b2, hB,
                                           BATCH, HID, HID, 1);
    out8_kernel<<<BATCH, 64, 0, stream>>>(hB, dec_w3, dec_b3, nn);
    solver_kernel<<<BATCH, 256, 0, stream>>>(nn, inp, ise, yub, ylb,
                                             P, Pd, Pdd, ws, outf);
}

// Round 3
// 397.574 us; speedup vs baseline: 2.0937x; 1.4910x over previous
//
#include <hip/hip_runtime.h>
#include <hip/hip_bf16.h>
#include <math.h>

// ---------------- problem constants ----------------
#define BATCH   1024
#define NUMPT   100
#define NVAR    11
#define NOBS    10
#define HID     1024
#define INPD    55
#define TRAJD   200
#define ENCIN   (INPD + TRAJD)   // 255
#define DECIN   (2 + INPD)       // 57

#define T_FIN_C   15.0f
#define K_P_C     20.0f
#define K_D_C     8.944271909999159f   // 2*sqrt(20)
#define K_P_V_C   20.0f
#define A_OBS_C   8.0f
#define B_OBS_C   4.2f
#define RHO_V_C      1.0f
#define RHO_PROJ_C   1.0f
#define RHO_LANE_C   100.0f
#define RHO_OBS_C    100.0f
#define RHO_OFFSET_C 1.0f
#define RHO_INEQ_C   100.0f
#define V_MIN_C   0.1f
#define V_MAX_C   30.0f
#define A_MAX_C   8.0f
#define MAXIT     20

// workspace layout (float offsets)
#define WS_INV1X  0      // 14x14
#define WS_INV1Y  256    // 15x15
#define WS_INV2X  512    // 14x14
#define WS_INV2Y  768    // 15x15
#define WS_SVD    1024   // 4x11 chunk-summed A_vd
#define WS_SPD    1088   // 4x11 chunk-summed A_pd
#define WS_QX     1152   // 11x11  Qx = cost2_x - I
#define WS_QY     1280   // 11x11  Qy = cost2_y - I
#define WS_BIG    2048

// ---------------------------------------------------------------------------
// Precompute: KKT matrices + inverses (GJ w/ partial pivoting), Qx/Qy,
// chunk-summed A_vd/A_pd. grid = 4 blocks, 256 threads.
// ---------------------------------------------------------------------------
__global__ __launch_bounds__(256) void precompute_kernel(
    const float* __restrict__ Pg, const float* __restrict__ Pdg,
    const float* __restrict__ Pddg, float* __restrict__ ws)
{
    __shared__ float sP[NUMPT*NVAR], sPd[NUMPT*NVAR], sPdd[NUMPT*NVAR];
    __shared__ float aug[15][31];
    __shared__ float fcol[15];
    __shared__ float s_pivinv;
    __shared__ int   s_pidx;
    const int tid = threadIdx.x, bid = blockIdx.x;

    for (int i = tid; i < NUMPT*NVAR; i += blockDim.x) {
        sP[i] = Pg[i]; sPd[i] = Pdg[i]; sPdd[i] = Pddg[i];
    }
    for (int i = tid; i < 15*31; i += blockDim.x) (&aug[0][0])[i] = 0.0f;
    __syncthreads();

    const int N = (bid == 0 || bid == 2) ? 14 : 15;

    if (tid < 121) {
        const int i = tid / 11, j = tid % 11;
        float s = 0.0f;
        if (bid == 0) {
            for (int t = 0; t < NUMPT; ++t) {
                float pdd_i = sPdd[t*NVAR+i], pdd_j = sPdd[t*NVAR+j];
                float av_i = pdd_i - K_P_V_C * sPd[t*NVAR+i];
                float av_j = pdd_j - K_P_V_C * sPd[t*NVAR+j];
                s += pdd_i*pdd_j + RHO_V_C * av_i*av_j;
            }
        } else if (bid == 1) {
            for (int t = 0; t < NUMPT; ++t) {
                float pdd_i = sPdd[t*NVAR+i], pdd_j = sPdd[t*NVAR+j];
                float ap_i = pdd_i - K_P_C*sP[t*NVAR+i] - K_D_C*sPd[t*NVAR+i];
                float ap_j = pdd_j - K_P_C*sP[t*NVAR+j] - K_D_C*sPd[t*NVAR+j];
                s += pdd_i*pdd_j + RHO_OFFSET_C * ap_i*ap_j;
            }
        } else {
            float obs_w = RHO_OBS_C * (float)NOBS;
            if (bid == 3) obs_w += RHO_LANE_C * 2.0f;
            for (int t = 0; t < NUMPT; ++t) {
                float p_i = sP[t*NVAR+i],   p_j = sP[t*NVAR+j];
                float pd_i = sPd[t*NVAR+i], pd_j = sPd[t*NVAR+j];
                float pdd_i = sPdd[t*NVAR+i], pdd_j = sPdd[t*NVAR+j];
                s += obs_w*p_i*p_j + RHO_INEQ_C*(pdd_i*pdd_j + pd_i*pd_j);
            }
            if (i == j) s += RHO_PROJ_C;
        }
        aug[i][j] = s;
    }
    if (tid < 11) {
        const int i = tid;
        float a0 = sP[i], a1 = sPd[i], a2 = sPdd[i];
        aug[i][11] = a0; aug[11][i] = a0;
        aug[i][12] = a1; aug[12][i] = a1;
        aug[i][13] = a2; aug[13][i] = a2;
        if (N == 15) { float a3 = sPd[99*NVAR + i]; aug[i][14] = a3; aug[14][i] = a3; }
    }
    if (tid < N) aug[tid][N + tid] = 1.0f;

    if (bid == 0 && tid < 44) {
        const int c = tid / 11, k = tid % 11;
        float sv = 0.0f, sp = 0.0f;
        for (int t = 25*c; t < 25*c + 25; ++t) {
            float p = sP[t*NVAR+k], pd = sPd[t*NVAR+k], pdd = sPdd[t*NVAR+k];
            sv += pdd - K_P_V_C * pd;
            sp += pdd - K_P_C * p - K_D_C * pd;
        }
        ws[WS_SVD + tid] = sv;
        ws[WS_SPD + tid] = sp;
    }
    __syncthreads();

    if ((bid == 2 || bid == 3) && tid < 121) {
        float v = aug[tid/11][tid%11];
        if (tid/11 == tid%11) v -= RHO_PROJ_C;
        ws[(bid == 2 ? WS_QX : WS_QY) + tid] = v;
    }

    for (int k = 0; k < N; ++k) {
        if (tid == 0) {
            int p = k; float best = fabsf(aug[k][k]);
            for (int i = k+1; i < N; ++i) {
                float v = fabsf(aug[i][k]);
                if (v > best) { best = v; p = i; }
            }
            s_pidx = p;
        }
        __syncthreads();
        const int p = s_pidx;
        if (p != k && tid < 2*N) {
            float tmp = aug[k][tid]; aug[k][tid] = aug[p][tid]; aug[p][tid] = tmp;
        }
        __syncthreads();
        if (tid == 0) s_pivinv = 1.0f / aug[k][k];
        __syncthreads();
        if (tid < 2*N) aug[k][tid] *= s_pivinv;
        __syncthreads();
        if (tid < N) fcol[tid] = (tid == k) ? 0.0f : aug[tid][k];
        __syncthreads();
        for (int idx = tid; idx < N*2*N; idx += blockDim.x) {
            const int i = idx / (2*N), j = idx % (2*N);
            if (i != k) aug[i][j] = fmaf(-fcol[i], aug[k][j], aug[i][j]);
        }
        __syncthreads();
    }

    float* dst = ws + (bid == 0 ? WS_INV1X : bid == 1 ? WS_INV1Y
                      : bid == 2 ? WS_INV2X : WS_INV2Y);
    for (int idx = tid; idx < N*N; idx += blockDim.x)
        dst[idx] = aug[idx / N][N + idx % N];
}

// ---------------------------------------------------------------------------
__global__ __launch_bounds__(256) void prep_kernel(
    const float* __restrict__ inp, const float* __restrict__ traj,
    const float* __restrict__ mean, const float* __restrict__ stdv,
    float* __restrict__ enc_in, float* __restrict__ dec_in)
{
    const int b = blockIdx.x, t = threadIdx.x;
    if (t < INPD) {
        float v = (inp[b*INPD + t] - mean[t]) / stdv[t];
        enc_in[b*ENCIN + t] = v;
        dec_in[b*DECIN + 2 + t] = v;
    } else if (t < ENCIN) {
        enc_in[b*ENCIN + t] = traj[b*TRAJD + (t - INPD)];
    }
}

// ---------------------------------------------------------------------------
// Split-K tiled fp32 GEMM. Partial[s] = A[:, ks:ke] @ W[ks:ke, :].
// 64x64 tile, BK=16, 256 threads, 4x4 micro-tile. blockIdx.z = K-chunk.
// Grid (N/64, M/64, S) -> 4 blocks/CU at S=4 => 16 waves/CU for latency
// hiding (round-2 showed 4 waves/CU = fully exposed load latency).
// ---------------------------------------------------------------------------
__global__ __launch_bounds__(256) void gemm_splitk(
    const float* __restrict__ A, const float* __restrict__ W,
    float* __restrict__ pbuf, int M, int N, int K, int chunk)
{
    __shared__ float As[16][68];   // [k][row]
    __shared__ float Bs[16][68];   // [k][col]
    const int tid = threadIdx.x;
    const int tx = tid & 15, ty = tid >> 4;
    const int row0 = blockIdx.y * 64, col0 = blockIdx.x * 64;
    const int s = blockIdx.z;
    const int kS = s * chunk;
    const int kE = min(K, kS + chunk);
    float* C = pbuf + (size_t)s * M * N;
    float acc[4][4] = {};

    for (int k0 = kS; k0 < kE; k0 += 16) {
        {   // A tile: 64 rows x 16 k, store k-major
            const int c = tid & 15, r = tid >> 4;
            const int kk = k0 + c;
            #pragma unroll
            for (int p = 0; p < 4; ++p) {
                const int rr = r + 16*p;
                As[c][rr] = (kk < kE) ? A[(size_t)(row0 + rr)*K + kk] : 0.0f;
            }
        }
        {   // W tile: 16 k x 64 cols
            const int n = tid & 63, c2 = tid >> 6;
            #pragma unroll
            for (int p = 0; p < 4; ++p) {
                const int kk = k0 + c2 + 4*p;
                Bs[c2 + 4*p][n] = (kk < kE) ? W[(size_t)kk*N + col0 + n] : 0.0f;
            }
        }
        __syncthreads();
        #pragma unroll
        for (int kk = 0; kk < 16; ++kk) {
            float4 a4 = *(const float4*)&As[kk][ty*4];
            float4 b4 = *(const float4*)&Bs[kk][tx*4];
            float a[4] = {a4.x, a4.y, a4.z, a4.w};
            float bb[4] = {b4.x, b4.y, b4.z, b4.w};
            #pragma unroll
            for (int i = 0; i < 4; ++i)
                #pragma unroll
                for (int j = 0; j < 4; ++j)
                    acc[i][j] = fmaf(a[i], bb[j], acc[i][j]);
        }
        __syncthreads();
    }
    #pragma unroll
    for (int i = 0; i < 4; ++i) {
        const int rr = row0 + ty*4 + i;
        #pragma unroll
        for (int j = 0; j < 4; ++j)
            C[(size_t)rr*N + col0 + tx*4 + j] = acc[i][j];
    }
}

// ---------------------------------------------------------------------------
// Sum S split-K partials + bias (+ReLU). N fixed = 1024 (all MLP outputs).
// float4-vectorized; 20 MB traffic at S=4 -> ~4 us.
// ---------------------------------------------------------------------------
__global__ __launch_bounds__(256) void reduce_bias_act(
    const float* __restrict__ pbuf, const float* __restrict__ bias,
    float* __restrict__ C, int S, int relu)
{
    const int idx4 = (blockIdx.x * 256 + threadIdx.x) * 4;   // < 1024*1024
    const int col = idx4 & (HID - 1);
    float4 a = *(const float4*)&pbuf[idx4];
    for (int s = 1; s < S; ++s) {
        const float4 b = *(const float4*)&pbuf[(size_t)s*BATCH*HID + idx4];
        a.x += b.x; a.y += b.y; a.z += b.z; a.w += b.w;
    }
    const float4 bi = *(const float4*)&bias[col];
    a.x += bi.x; a.y += bi.y; a.z += bi.z; a.w += bi.w;
    if (relu) {
        a.x = fmaxf(a.x, 0.0f); a.y = fmaxf(a.y, 0.0f);
        a.z = fmaxf(a.z, 0.0f); a.w = fmaxf(a.w, 0.0f);
    }
    *(float4*)&C[idx4] = a;
}

// ---------------------------------------------------------------------------
__global__ __launch_bounds__(64) void z_kernel(
    const float* __restrict__ h, const float* __restrict__ wmu,
    const float* __restrict__ bmu, const float* __restrict__ wlv,
    const float* __restrict__ blv, const float* __restrict__ eps,
    float* __restrict__ dec_in)
{
    const int b = blockIdx.x, lane = threadIdx.x;
    float a0 = 0, a1 = 0, a2 = 0, a3 = 0;
    for (int hh = lane; hh < HID; hh += 64) {
        float v = h[b*HID + hh];
        a0 = fmaf(v, wmu[hh*2 + 0], a0);
        a1 = fmaf(v, wmu[hh*2 + 1], a1);
        a2 = fmaf(v, wlv[hh*2 + 0], a2);
        a3 = fmaf(v, wlv[hh*2 + 1], a3);
    }
    #pragma unroll
    for (int off = 32; off; off >>= 1) {
        a0 += __shfl_down(a0, off);
        a1 += __shfl_down(a1, off);
        a2 += __shfl_down(a2, off);
        a3 += __shfl_down(a3, off);
    }
    if (lane == 0) {
        float mu0 = a0 + bmu[0], mu1 = a1 + bmu[1];
        float lv0 = a2 + blv[0], lv1 = a3 + blv[1];
        dec_in[b*DECIN + 0] = fmaf(expf(0.5f*lv0), eps[b*2 + 0], mu0);
        dec_in[b*DECIN + 1] = fmaf(expf(0.5f*lv1), eps[b*2 + 1], mu1);
    }
}

// ---------------------------------------------------------------------------
__global__ __launch_bounds__(64) void out8_kernel(
    const float* __restrict__ h, const float* __restrict__ w3,
    const float* __restrict__ b3, float* __restrict__ nn_out)
{
    const int b = blockIdx.x, lane = threadIdx.x;
    float acc[8] = {};
    for (int hh = lane; hh < HID; hh += 64) {
        float v = h[b*HID + hh];
        #pragma unroll
        for (int j = 0; j < 8; ++j) acc[j] = fmaf(v, w3[hh*8 + j], acc[j]);
    }
    #pragma unroll
    for (int j = 0; j < 8; ++j)
        #pragma unroll
        for (int off = 32; off; off >>= 1) acc[j] += __shfl_down(acc[j], off);
    if (lane == 0)
        for (int j = 0; j < 8; ++j) nn_out[b*8 + j] = acc[j] + b3[j];
}

// ---------------------------------------------------------------------------
// Batched ADMM solver (see round-2 structure).
// ---------------------------------------------------------------------------
__global__ __launch_bounds__(256) void solver_kernel(
    const float* __restrict__ nn_out, const float* __restrict__ inp,
    const float* __restrict__ ise, const float* __restrict__ yub_p,
    const float* __restrict__ ylb_p,
    const float* __restrict__ Pg, const float* __restrict__ Pdg,
    const float* __restrict__ Pddg,
    const float* __restrict__ ws, float* __restrict__ out)
{
    __shared__ float sP[NUMPT*NVAR], sPd[NUMPT*NVAR], sPdd[NUMPT*NVAR];
    __shared__ float i2x[196], i2y[225];
    __shared__ float Qx[121], Qy[121];
    __shared__ float rows[900];
    __shared__ float part[NVAR][20];
    __shared__ float cxb[2][NVAR], cyb[2][NVAR];
    __shared__ float lx[NVAR], ly[NVAR], cbx[NVAR], cby[NVAR];
    __shared__ float linx[NVAR], liny[NVAR];
    __shared__ float obsx[NOBS], obsy[NOBS], obsvx[NOBS], obsvy[NOBS];
    __shared__ float nn[8], lcx[NVAR], lcy[NVAR];

    float* R_SX0 = rows +   0;
    float* R_SX1 = rows + 100;
    float* R_SY0 = rows + 200;
    float* R_SY1 = rows + 300;
    float* R_VX  = rows + 400;
    float* R_VY  = rows + 500;
    float* R_AX  = rows + 600;
    float* R_AY  = rows + 700;
    float* R_LN  = rows + 800;

    const int b = blockIdx.x, tid = threadIdx.x;

    for (int i = tid; i < NUMPT*NVAR; i += 256) {
        sP[i] = Pg[i]; sPd[i] = Pdg[i]; sPdd[i] = Pddg[i];
    }
    for (int i = tid; i < 196; i += 256) i2x[i] = ws[WS_INV2X + i];
    for (int i = tid; i < 225; i += 256) i2y[i] = ws[WS_INV2Y + i];
    for (int i = tid; i < 121; i += 256) { Qx[i] = ws[WS_QX + i]; Qy[i] = ws[WS_QY + i]; }
    float* i1x = rows;          // 196 (aliased; consumed before phase A)
    float* i1y = rows + 200;    // 225
    for (int i = tid; i < 196; i += 256) i1x[i] = ws[WS_INV1X + i];
    for (int i = tid; i < 225; i += 256) i1y[i] = ws[WS_INV1Y + i];
    if (tid < NOBS) {
        obsx[tid]  = inp[b*INPD + 5 + 5*tid];
        obsy[tid]  = inp[b*INPD + 6 + 5*tid];
        obsvx[tid] = inp[b*INPD + 7 + 5*tid];
        obsvy[tid] = inp[b*INPD + 8 + 5*tid];
    }
    if (tid < 8) nn[tid] = nn_out[b*8 + tid];
    __syncthreads();

    const float vx0 = ise[b*4 + 2], vy0 = ise[b*4 + 3];
    const float yub = yub_p[b], ylb = ylb_p[b];

    if (tid < NVAR) {
        float sx_ = 0.0f, sy_ = 0.0f;
        #pragma unroll
        for (int c = 0; c < 4; ++c) {
            sx_ = fmaf(nn[c],     ws[WS_SVD + c*11 + tid], sx_);
            sy_ = fmaf(nn[4 + c], ws[WS_SPD + c*11 + tid], sy_);
        }
        lcx[tid] = RHO_V_C * K_P_V_C * sx_;
        lcy[tid] = RHO_OFFSET_C * K_P_C * sy_;
    }
    __syncthreads();
    if (tid < NVAR) {
        const int k = tid;
        float ax = vx0 * i1x[k*14 + 12];
        float ay = vy0 * i1y[k*15 + 12];
        #pragma unroll
        for (int j = 0; j < NVAR; ++j) {
            ax = fmaf(-lcx[j], i1x[k*14 + j], ax);
            ay = fmaf(-lcy[j], i1y[k*15 + j], ay);
        }
        cbx[k] = ax; cby[k] = ay;
        cxb[0][k] = ax; cyb[0][k] = ay;
        lx[k] = 0.0f; ly[k] = 0.0f;
    }
    __syncthreads();

    int cur = 0;
    for (int it = 0; it < MAXIT; ++it) {
        const float* cxc = cxb[cur];
        const float* cyc = cyb[cur];

        if (tid < 2*NUMPT) {
            const int t = tid >> 1, h = tid & 1;
            const float* rP = &sP[t*NVAR];
            float px = 0, py = 0;
            #pragma unroll
            for (int k = 0; k < NVAR; ++k) {
                px = fmaf(cxc[k], rP[k], px);
                py = fmaf(cyc[k], rP[k], py);
            }
            const float tt = (float)t * (T_FIN_C / 99.0f);

            if (h == 0) {
                const float* rPd = &sPd[t*NVAR];
                const float* rPdd = &sPdd[t*NVAR];
                float pxd = 0, pxdd = 0, pyd = 0, pydd = 0;
                #pragma unroll
                for (int k = 0; k < NVAR; ++k) {
                    float cxv = cxc[k], cyv = cyc[k];
                    pxd  = fmaf(cxv, rPd[k],  pxd);
                    pxdd = fmaf(cxv, rPdd[k], pxdd);
                    pyd  = fmaf(cyv, rPd[k],  pyd);
                    pydd = fmaf(cyv, rPdd[k], pydd);
                }
                float rv2 = pxd*pxd + pyd*pyd, cv, sv, rv;
                if (rv2 > 0.0f) { float ri = rsqrtf(rv2); rv = rv2*ri; cv = pxd*ri; sv = pyd*ri; }
                else            { rv = 0.0f; cv = 1.0f; sv = 0.0f; }
                float dv = fminf(fmaxf(rv, V_MIN_C), V_MAX_C);
                R_VX[t] = pxd - dv*cv;  R_VY[t] = pyd - dv*sv;
                float ra2 = pxdd*pxdd + pydd*pydd, caa, saa, ra;
                if (ra2 > 0.0f) { float ri = rsqrtf(ra2); ra = ra2*ri; caa = pxdd*ri; saa = pydd*ri; }
                else            { ra = 0.0f; caa = 1.0f; saa = 0.0f; }
                float da = fminf(ra, A_MAX_C);
                R_AX[t] = pxdd - da*caa;  R_AY[t] = pydd - da*saa;
                R_LN[t] = fmaxf(0.0f, py - yub) - fmaxf(0.0f, ylb - py);
            }
            float srx = 0, sry = 0;
            const int o0 = h ? 4 : 0, o1 = h ? NOBS : 4;
            for (int o = o0; o < o1; ++o) {
                float xo = fmaf(obsvx[o], tt, obsx[o]);
                float yo = fmaf(obsvy[o], tt, obsy[o]);
                float wc = px - xo, wsv = py - yo;
                float aw = A_OBS_C * wsv, bw = B_OBS_C * wc;
                float r2 = aw*aw + bw*bw;
                float ca, sa;
                if (r2 > 0.0f) { float ri = rsqrtf(r2); ca = bw*ri; sa = aw*ri; }
                else           { ca = 1.0f; sa = 0.0f; }
                float c1 = RHO_OBS_C * (A_OBS_C*A_OBS_C*ca*ca + B_OBS_C*B_OBS_C*sa*sa);
                float c2 = RHO_OBS_C * (A_OBS_C*wc*ca + B_OBS_C*wsv*sa);
                float d_o = fmaxf(1.0f, c2 / c1);
                srx += wc - A_OBS_C * d_o * ca;
                sry += wsv - B_OBS_C * d_o * sa;
            }
            if (h == 0) { R_SX0[t] = srx; R_SY0[t] = sry; }
            else        { R_SX1[t] = srx; R_SY1[t] = sry; }
        }
        __syncthreads();

        if (tid < 198) {
            const int k = tid / 18, u = tid - k*18;
            const float* rp; const float* bp; int t0;
            if (u < 4)       { rp = (u & 2) ? R_SX1 : R_SX0; bp = sP;   t0 = (u & 1)*50; }
            else if (u < 6)  { rp = R_AX; bp = sPdd; t0 = (u - 4)*50; }
            else if (u < 8)  { rp = R_VX; bp = sPd;  t0 = (u - 6)*50; }
            else if (u < 12) { rp = (u & 2) ? R_SY1 : R_SY0; bp = sP;   t0 = (u & 1)*50; }
            else if (u < 14) { rp = R_AY; bp = sPdd; t0 = (u - 12)*50; }
            else if (u < 16) { rp = R_VY; bp = sPd;  t0 = (u - 14)*50; }
            else             { rp = R_LN; bp = sP;   t0 = (u - 16)*50; }
            float s = 0.0f;
            for (int t = t0; t < t0 + 50; ++t)
                s = fmaf(rp[t], bp[t*NVAR + k], s);
            part[k][u] = s;
        }
        __syncthreads();

        if (tid < 22) {
            const int k = (tid < 11) ? tid : tid - 11;
            if (tid < 11) {
                float s = 0.0f;
                #pragma unroll
                for (int u = 0; u < 8; ++u) s += part[k][u];
                float ux = RHO_OBS_C * s;
                float q = 0.0f;
                #pragma unroll
                for (int j = 0; j < NVAR; ++j) q = fmaf(Qx[k*11 + j], cxc[j], q);
                float l = lx[k];
                lx[k] = l - ux;
                linx[k] = -l + 2.0f*ux - RHO_PROJ_C*cbx[k] - q;
            } else {
                float s = 0.0f;
                #pragma unroll
                for (int u = 8; u < 18; ++u) s += part[k][u];
                float uy = RHO_OBS_C * s;
                float q = 0.0f;
                #pragma unroll
                for (int j = 0; j < NVAR; ++j) q = fmaf(Qy[k*11 + j], cyc[j], q);
                float l = ly[k];
                ly[k] = l - uy;
                liny[k] = -l + 2.0f*uy - RHO_PROJ_C*cby[k] - q;
            }
        }
        __syncthreads();

        if (tid < 22) {
            const int k = (tid < 11) ? tid : tid - 11;
            if (tid < 11) {
                float a = vx0 * i2x[k*14 + 12];
                #pragma unroll
                for (int j = 0; j < NVAR; ++j) a = fmaf(-linx[j], i2x[k*14 + j], a);
                cxb[cur ^ 1][k] = a;
            } else {
                float a = vy0 * i2y[k*15 + 12];
                #pragma unroll
                for (int j = 0; j < NVAR; ++j) a = fmaf(-liny[j], i2y[k*15 + j], a);
                cyb[cur ^ 1][k] = a;
            }
        }
        cur ^= 1;
        __syncthreads();
    }

    if (tid < NVAR) {
        out[b*22 + tid]      = cxb[cur][tid];
        out[b*22 + 11 + tid] = cyb[cur][tid];
    }
}

// ---------------------------------------------------------------------------
extern "C" void kernel_launch(void* const* d_in, const int* in_sizes, int n_in,
                              void* d_out, int out_size, void* d_ws, size_t ws_size,
                              hipStream_t stream)
{
    (void)in_sizes; (void)n_in; (void)out_size;
    const float* inp    = (const float*)d_in[0];
    const float* ise    = (const float*)d_in[1];
    const float* traj   = (const float*)d_in[2];
    const float* yub    = (const float*)d_in[3];
    const float* ylb    = (const float*)d_in[4];
    const float* eps    = (const float*)d_in[5];
    const float* enc_w1 = (const float*)d_in[6];
    const float* enc_b1 = (const float*)d_in[7];
    const float* enc_w2 = (const float*)d_in[8];
    const float* enc_b2 = (const float*)d_in[9];
    const float* wmu    = (const float*)d_in[10];
    const float* bmu    = (const float*)d_in[11];
    const float* wlv    = (const float*)d_in[12];
    const float* blv    = (const float*)d_in[13];
    const float* dec_w1 = (const float*)d_in[14];
    const float* dec_b1 = (const float*)d_in[15];
    const float* dec_w2 = (const float*)d_in[16];
    const float* dec_b2 = (const float*)d_in[17];
    const float* dec_w3 = (const float*)d_in[18];
    const float* dec_b3 = (const float*)d_in[19];
    const float* P      = (const float*)d_in[20];
    const float* Pd     = (const float*)d_in[21];
    const float* Pdd    = (const float*)d_in[22];
    const float* mean   = (const float*)d_in[23];
    const float* stdv   = (const float*)d_in[24];

    float* ws     = (float*)d_ws;
    float* enc_in = ws + WS_BIG;                     // B x 255
    float* dec_in = enc_in + (size_t)BATCH * ENCIN;  // B x 57
    float* hA     = dec_in + (size_t)BATCH * DECIN;  // B x 1024
    float* hB     = hA + (size_t)BATCH * HID;        // B x 1024
    float* nn     = hB + (size_t)BATCH * HID;        // B x 8
    float* pbuf   = nn + (size_t)BATCH * 8;          // S x (B x 1024)
    float* outf   = (float*)d_out;

    // split-K factor clamped by available workspace (constant across calls)
    const size_t base_bytes = ((size_t)(pbuf - ws)) * sizeof(float);
    const size_t avail = (ws_size > base_bytes) ? ws_size - base_bytes : 0;
    const size_t one = (size_t)BATCH * HID * sizeof(float);
    int S = (int)(avail / one);
    if (S > 4) S = 4;
    if (S < 1) S = 1;   // degenerate fallback (pbuf aliases nothing valid; ws must hold >= 1)
    auto chunk_of = [&](int K) { return ((K + S - 1) / S + 15) & ~15; };

    precompute_kernel<<<4, 256, 0, stream>>>(P, Pd, Pdd, ws);
    prep_kernel<<<BATCH, 256, 0, stream>>>(inp, traj, mean, stdv, enc_in, dec_in);

    dim3 gr(HID/64, BATCH/64, S);
    const int rblocks = BATCH * HID / 4 / 256;   // 1024

    gemm_splitk<<<gr, 256, 0, stream>>>(enc_in, enc_w1, pbuf, BATCH, HID, ENCIN, chunk_of(ENCIN));
    reduce_bias_act<<<rblocks, 256, 0, stream>>>(pbuf, enc_b1, hA, S, 1);
    gemm_splitk<<<gr, 256, 0, stream>>>(hA, enc_w2, pbuf, BATCH, HID, HID, chunk_of(HID));
    reduce_bias_act<<<rblocks, 256, 0, stream>>>(pbuf, enc_b2, hB, S, 1);
    z_kernel<<<BATCH, 64, 0, stream>>>(hB, wmu, bmu, wlv, blv, eps, dec_in);
    gemm_splitk<<<gr, 256, 0, stream>>>(dec_in, dec_w1, pbuf, BATCH, HID, DECIN, chunk_of(DECIN));
    reduce_bias_act<<<rblocks, 256, 0, stream>>>(pbuf, dec_b1, hA, S, 1);
    gemm_splitk<<<gr, 256, 0, stream>>>(hA, dec_w2, pbuf, BATCH, HID, HID, chunk_of(HID));
    reduce_bias_act<<<rblocks, 256, 0, stream>>>(pbuf, dec_b2, hB, S, 1);
    out8_kernel<<<BATCH, 64, 0, stream>>>(hB, dec_w3, dec_b3, nn);
    solver_kernel<<<BATCH, 256, 0, stream>>>(nn, inp, ise, yub, ylb,
                                             P, Pd, Pdd, ws, outf);
}